// Round 7
// baseline (2222.384 us; speedup 1.0000x reference)
//
#include <hip/hip_runtime.h>
#include <hip/hip_bf16.h>
#include <stdint.h>

// ---------------------------------------------------------------------------
// Marching tetrahedra (DMTet) on MI355X — round 7: OUTPUT IS FLOAT32.
//
// Harness facts (hard-won):
//   - integer inputs arrive as int32 (int64 tet_fx4 -> const int*)
//   - d_out is FLOAT32 (mixed-dtype tuple -> "else float*"); 46M f32 = 184MB
//   - d_ws >= 74MB (rounds 4-6 demonstrably ran with WS_NEED=73.7MB)
//
// Pipeline (reproduces jnp.unique sorted-rank semantics exactly):
//   k_count    : per valid tet, histogram edge min-endpoint 'a' (200k buckets)
//   k_bsumA/B/C: exclusive scan of bucket counts -> bstart[] / scatter cursor
//   k_scatter  : scatter packed key (a<<41|b<<23|origIdx) into bucket regions
//   k_sort     : per-bucket insertion sort  (=> globally sorted by (a,b))
//   k_s1/s2/s3 : 3-stage split scan over sorted edges (unique heads, crossing
//                heads); s3 writes mask, interpolated verts, edgeMap
//   k_faces    : tri-table lookup -> faces/face_mask/uv_idx
//   k_uv       : deterministic uv grid
// ---------------------------------------------------------------------------

#define NV 200000
#define NT 1000000
#define KE 6000000                        // 6 * NT; structural max of M

#define CHUNK 4096
#define EPT 16
#define NBLK ((KE + CHUNK - 1) / CHUNK)   // 1465
#define S2C  ((NBLK + 255) / 256)         // 6
#define NB2  ((NV + 255) / 256)           // 782

// out element offsets (f32 elements)
#define OFF_MASK  18000000
#define OFF_FACES 24000000
#define OFF_FMASK 30000000
#define OFF_UVS   32000000
#define OFF_UVIDX 40000000
#define NROW_UV   4000000

// d_ws layout (bytes)
#define WS_CURSOR   0
#define WS_BSTART   819200
#define WS_PART     1638400
#define WS_PBASE    1654784
#define WS_BSUM     1671168
#define WS_EDGEMAP  1703936        // 24,000,000 B
#define WS_PK       25703936       // 48,000,000 B (KE u64)
#define WS_NEED     73703936

typedef unsigned long long u64;

__constant__ signed char c_tri[16][6] = {
  {-1,-1,-1,-1,-1,-1},{1,0,2,-1,-1,-1},{4,0,3,-1,-1,-1},{1,4,2,1,3,4},
  {3,1,5,-1,-1,-1},{2,3,0,2,5,3},{1,4,0,1,5,4},{4,2,5,-1,-1,-1},
  {4,5,2,-1,-1,-1},{4,1,0,4,5,1},{3,2,0,3,5,2},{1,3,5,-1,-1,-1},
  {4,1,2,4,3,1},{3,0,4,-1,-1,-1},{2,0,1,-1,-1,-1},{-1,-1,-1,-1,-1,-1}};
__constant__ signed char c_ntri[16] = {0,1,1,2,1,2,2,1,1,2,2,1,2,1,1,0};

// ---------------------------------------------------------------------------
__global__ void k_count(const int4* __restrict__ tet,
                        const float* __restrict__ sdf,
                        int* __restrict__ cnt) {
  int f = blockIdx.x * 256 + threadIdx.x;
  if (f >= NT) return;
  int4 t = tet[f];
  int v0 = t.x, v1 = t.y, v2 = t.z, v3 = t.w;
  int s = (sdf[v0] > 0.f) + (sdf[v1] > 0.f) + (sdf[v2] > 0.f) + (sdf[v3] > 0.f);
  if (s == 0 || s == 4) return;
#define EDGE_CNT(va, vb) { int lo = (va < vb) ? va : vb; atomicAdd(&cnt[lo], 1); }
  EDGE_CNT(v0, v1); EDGE_CNT(v0, v2); EDGE_CNT(v0, v3);
  EDGE_CNT(v1, v2); EDGE_CNT(v1, v3); EDGE_CNT(v2, v3);
#undef EDGE_CNT
}

// ---------------------------------------------------------------------------
__global__ void k_bsumA(const int* __restrict__ cnt, int* __restrict__ bsum) {
  __shared__ int sh[256];
  int i = blockIdx.x * 256 + threadIdx.x;
  sh[threadIdx.x] = (i < NV) ? cnt[i] : 0;
  __syncthreads();
  for (int off = 128; off > 0; off >>= 1) {
    if (threadIdx.x < off) sh[threadIdx.x] += sh[threadIdx.x + off];
    __syncthreads();
  }
  if (threadIdx.x == 0) bsum[blockIdx.x] = sh[0];
}

__global__ void k_bsumB(int* __restrict__ bsum, int* __restrict__ bstart) {
  __shared__ int sh[1024];
  int t = threadIdx.x;
  sh[t] = (t < NB2) ? bsum[t] : 0;
  __syncthreads();
  for (int off = 1; off < 1024; off <<= 1) {
    int v = sh[t];
    int add = (t >= off) ? sh[t - off] : 0;
    __syncthreads();
    sh[t] = v + add;
    __syncthreads();
  }
  if (t < NB2) bsum[t] = (t > 0) ? sh[t - 1] : 0;   // exclusive block bases
  if (t == 0) bstart[NV] = sh[1023];                // total M
}

__global__ void k_bsumC(int* __restrict__ cnt, const int* __restrict__ bsum,
                        int* __restrict__ bstart) {
  __shared__ int sh[256];
  int t = threadIdx.x;
  int i = blockIdx.x * 256 + t;
  int c = (i < NV) ? cnt[i] : 0;
  sh[t] = c;
  __syncthreads();
  for (int off = 1; off < 256; off <<= 1) {
    int v = sh[t];
    int add = (t >= off) ? sh[t - off] : 0;
    __syncthreads();
    sh[t] = v + add;
    __syncthreads();
  }
  if (i < NV) {
    int ex = bsum[blockIdx.x] + ((t > 0) ? sh[t - 1] : 0);
    bstart[i] = ex;
    cnt[i] = ex;   // becomes the scatter cursor
  }
}

// ---------------------------------------------------------------------------
__global__ void k_scatter(const int4* __restrict__ tet,
                          const float* __restrict__ sdf,
                          int* __restrict__ cursor,
                          u64* __restrict__ pk) {
  int f = blockIdx.x * 256 + threadIdx.x;
  if (f >= NT) return;
  int4 t = tet[f];
  int v0 = t.x, v1 = t.y, v2 = t.z, v3 = t.w;
  int s = (sdf[v0] > 0.f) + (sdf[v1] > 0.f) + (sdf[v2] > 0.f) + (sdf[v3] > 0.f);
  if (s == 0 || s == 4) return;
  int base = f * 6;
#define EDGE_SC(e, va, vb) { int lo, hi; if (va < vb) { lo = va; hi = vb; } else { lo = vb; hi = va; } \
    int p = atomicAdd(&cursor[lo], 1); \
    pk[p] = ((u64)lo << 41) | ((u64)hi << 23) | (u64)(base + e); }
  EDGE_SC(0, v0, v1); EDGE_SC(1, v0, v2); EDGE_SC(2, v0, v3);
  EDGE_SC(3, v1, v2); EDGE_SC(4, v1, v3); EDGE_SC(5, v2, v3);
#undef EDGE_SC
}

// ---------------------------------------------------------------------------
__global__ void k_sort(const int* __restrict__ bstart, u64* __restrict__ pk) {
  int a = blockIdx.x * 256 + threadIdx.x;
  if (a >= NV) return;
  int s = bstart[a], e = bstart[a + 1];
  for (int i = s + 1; i < e; i++) {
    u64 key = pk[i];
    int j = i - 1;
    while (j >= s && pk[j] > key) { pk[j + 1] = pk[j]; j--; }
    pk[j + 1] = key;
  }
}

// ---------------------------------------------------------------------------
__global__ void k_s1(const u64* __restrict__ pk,
                     const float* __restrict__ sdf, const int* __restrict__ bstart,
                     int2* __restrict__ part) {
  const int M = bstart[NV];
  int tid = threadIdx.x;
  int base = blockIdx.x * CHUNK + tid * EPT;
  int h = 0, c = 0;
  for (int k = 0; k < EPT; k++) {
    int i = base + k;
    if (i >= M) break;
    u64 p = pk[i];
    bool head = (i == 0) || ((pk[i - 1] >> 23) != (p >> 23));
    if (head) {
      int a = (int)(p >> 41);
      int b = (int)((p >> 23) & 0x3FFFF);
      h++;
      if ((sdf[a] > 0.f) != (sdf[b] > 0.f)) c++;
    }
  }
  __shared__ int shH[256], shC[256];
  shH[tid] = h; shC[tid] = c;
  __syncthreads();
  for (int off = 128; off > 0; off >>= 1) {
    if (tid < off) { shH[tid] += shH[tid + off]; shC[tid] += shC[tid + off]; }
    __syncthreads();
  }
  if (tid == 0) part[blockIdx.x] = make_int2(shH[0], shC[0]);
}

__global__ void k_s2(const int2* __restrict__ part, int2* __restrict__ pbase) {
  __shared__ int shH[256], shC[256];
  int t = threadIdx.x;
  int b0 = t * S2C, b1 = min(b0 + S2C, NBLK);
  int h = 0, c = 0;
  for (int i = b0; i < b1; i++) { int2 p = part[i]; h += p.x; c += p.y; }
  shH[t] = h; shC[t] = c;
  __syncthreads();
  for (int off = 1; off < 256; off <<= 1) {
    int vH = shH[t], vC = shC[t];
    int aH = (t >= off) ? shH[t - off] : 0;
    int aC = (t >= off) ? shC[t - off] : 0;
    __syncthreads();
    shH[t] = vH + aH; shC[t] = vC + aC;
    __syncthreads();
  }
  int hb = (t > 0) ? shH[t - 1] : 0;
  int cb = (t > 0) ? shC[t - 1] : 0;
  for (int i = b0; i < b1; i++) {
    int2 p = part[i];
    pbase[i] = make_int2(hb, cb);
    hb += p.x; cb += p.y;
  }
}

__global__ void k_s3(const u64* __restrict__ pk,
                     const float* __restrict__ sdf, const float* __restrict__ pos,
                     const int* __restrict__ bstart, const int2* __restrict__ pbase,
                     int* __restrict__ edgeMap, float* __restrict__ out) {
  const int M = bstart[NV];
  int tid = threadIdx.x;
  int base = blockIdx.x * CHUNK + tid * EPT;
  int h = 0, c = 0;
  for (int k = 0; k < EPT; k++) {
    int i = base + k;
    if (i >= M) break;
    u64 p = pk[i];
    bool head = (i == 0) || ((pk[i - 1] >> 23) != (p >> 23));
    if (head) {
      int a = (int)(p >> 41);
      int b = (int)((p >> 23) & 0x3FFFF);
      h++;
      if ((sdf[a] > 0.f) != (sdf[b] > 0.f)) c++;
    }
  }
  __shared__ int shH[256], shC[256];
  shH[tid] = h; shC[tid] = c;
  __syncthreads();
  for (int off = 1; off < 256; off <<= 1) {
    int vH = shH[tid], vC = shC[tid];
    int aH = (tid >= off) ? shH[tid - off] : 0;
    int aC = (tid >= off) ? shC[tid - off] : 0;
    __syncthreads();
    shH[tid] = vH + aH; shC[tid] = vC + aC;
    __syncthreads();
  }
  int2 bb = pbase[blockIdx.x];
  int hRun = bb.x + ((tid > 0) ? shH[tid - 1] : 0);
  int cRun = bb.y + ((tid > 0) ? shC[tid - 1] : 0);
  for (int k = 0; k < EPT; k++) {
    int i = base + k;
    if (i >= M) break;
    u64 p = pk[i];
    int a = (int)(p >> 41);
    int b = (int)((p >> 23) & 0x3FFFF);
    int oidx = (int)(p & 0x7FFFFF);
    bool head = (i == 0) || ((pk[i - 1] >> 23) != (p >> 23));
    bool cross = (sdf[a] > 0.f) != (sdf[b] > 0.f);
    if (head) { hRun++; if (cross) cRun++; }
    edgeMap[oidx] = cross ? (cRun - 1) : -1;
    if (head && cross) {
      out[OFF_MASK + (hRun - 1)] = 1.0f;
      int m = cRun - 1;
      float s0 = sdf[a], s1 = sdf[b];
      float inv = 1.0f / (s0 - s1);
      float w0 = -s1 * inv, w1 = s0 * inv;
      const float* pa = pos + 3 * a;
      const float* pb = pos + 3 * b;
      out[3 * m + 0] = pa[0] * w0 + pb[0] * w1;
      out[3 * m + 1] = pa[1] * w0 + pb[1] * w1;
      out[3 * m + 2] = pa[2] * w0 + pb[2] * w1;
    }
  }
}

// ---------------------------------------------------------------------------
__global__ void k_faces(const int4* __restrict__ tet,
                        const float* __restrict__ sdf,
                        const int* __restrict__ edgeMap,
                        float* __restrict__ out) {
  int f = blockIdx.x * 256 + threadIdx.x;
  if (f >= NT) return;
  int4 t = tet[f];
  int v0 = t.x, v1 = t.y, v2 = t.z, v3 = t.w;
  int o = (int)(sdf[v0] > 0.f) | ((int)(sdf[v1] > 0.f) << 1) |
          ((int)(sdf[v2] > 0.f) << 2) | ((int)(sdf[v3] > 0.f) << 3);
  int nt = c_ntri[o];
  int base6 = f * 6;
  float* fo = out + OFF_FACES + base6;
  float* uo = out + OFF_UVIDX + base6;
  float f4 = (float)(4 * f);
#pragma unroll
  for (int tr = 0; tr < 2; tr++) {
    bool fm = tr < nt;
    float a0 = -1.f, a1 = -1.f, a2 = -1.f;
    if (fm) {
      int e0 = c_tri[o][3 * tr + 0];
      int e1 = c_tri[o][3 * tr + 1];
      int e2 = c_tri[o][3 * tr + 2];
      a0 = (float)edgeMap[base6 + e0];
      a1 = (float)edgeMap[base6 + e1];
      a2 = (float)edgeMap[base6 + e2];
    }
    fo[3 * tr + 0] = a0;
    fo[3 * tr + 1] = a1;
    fo[3 * tr + 2] = a2;
    out[OFF_FMASK + f * 2 + tr] = fm ? 1.f : 0.f;
    uo[3 * tr + 0] = f4;
    uo[3 * tr + 1] = f4 + (float)(tr + 1);
    uo[3 * tr + 2] = f4 + (float)(tr + 2);
  }
}

// ---------------------------------------------------------------------------
__global__ void k_uv(float* __restrict__ out) {
  int r = blockIdx.x * 256 + threadIdx.x;
  if (r >= NROW_UV) return;
  int cell = r >> 2, c = r & 3;
  int i = cell / 1000, j = cell % 1000;
  const float STEP = 0.999f / 999.0f;   // jnp.linspace(0, 1-1/1000, 1000) step
  const float PAD = 0.0009f;            // 0.9 / 1000
  float x = j * STEP + ((c == 1 || c == 2) ? PAD : 0.f);
  float y = i * STEP + ((c >= 2) ? PAD : 0.f);
  out[OFF_UVS + 2 * r]     = x;
  out[OFF_UVS + 2 * r + 1] = y;
}

// ---------------------------------------------------------------------------
extern "C" void kernel_launch(void* const* d_in, const int* in_sizes, int n_in,
                              void* d_out, int out_size, void* d_ws, size_t ws_size,
                              hipStream_t stream) {
  const float* pos = (const float*)d_in[0];
  const float* sdf = (const float*)d_in[1];
  const int4*  tet = (const int4*)d_in[2];   // int64 in reference -> int32 here
  float* out = (float*)d_out;                // mixed-dtype tuple -> float32 out

  if (ws_size < (size_t)WS_NEED) return;     // decodable clean-fail if ws too small

  char* ws = (char*)d_ws;
  int*  cursor  = (int*)(ws + WS_CURSOR);
  int*  bstart  = (int*)(ws + WS_BSTART);
  int2* part    = (int2*)(ws + WS_PART);
  int2* pbase   = (int2*)(ws + WS_PBASE);
  int*  bsum    = (int*)(ws + WS_BSUM);
  int*  edgeMap = (int*)(ws + WS_EDGEMAP);
  u64*  pk      = (u64*)(ws + WS_PK);

  // zero bucket counters + the sparse-written output regions (verts + mask)
  (void)hipMemsetAsync(cursor, 0, (size_t)NV * sizeof(int), stream);
  (void)hipMemsetAsync(out, 0, (size_t)OFF_FACES * sizeof(float), stream);

  const int TB = 256;
  k_count  <<<(NT + TB - 1) / TB, TB, 0, stream>>>(tet, sdf, cursor);
  k_bsumA  <<<NB2, TB, 0, stream>>>(cursor, bsum);
  k_bsumB  <<<1, 1024, 0, stream>>>(bsum, bstart);
  k_bsumC  <<<NB2, TB, 0, stream>>>(cursor, bsum, bstart);
  k_scatter<<<(NT + TB - 1) / TB, TB, 0, stream>>>(tet, sdf, cursor, pk);
  k_sort   <<<(NV + TB - 1) / TB, TB, 0, stream>>>(bstart, pk);
  k_s1     <<<NBLK, TB, 0, stream>>>(pk, sdf, bstart, part);
  k_s2     <<<1, TB, 0, stream>>>(part, pbase);
  k_s3     <<<NBLK, TB, 0, stream>>>(pk, sdf, pos, bstart, pbase, edgeMap, out);
  k_faces  <<<(NT + TB - 1) / TB, TB, 0, stream>>>(tet, sdf, edgeMap, out);
  k_uv     <<<(NROW_UV + TB - 1) / TB, TB, 0, stream>>>(out);
}